// Round 1
// baseline (7142.165 us; speedup 1.0000x reference)
//
#include <hip/hip_runtime.h>

// GraphSAGE 3-layer, eval mode. All fp32.
// N0=400000, N1=100000, N2=20000, N3=4096; F=256 (in/hid), 128 out
// E0=1.5M, E1=200K, E2=40960

static constexpr int kN1 = 100000;
static constexpr int kN2 = 20000;
static constexpr int kN3 = 4096;
static constexpr int kE0 = 1500000;
static constexpr int kE1 = 200000;
static constexpr int kE2 = 40960;
static constexpr int kF  = 256;   // IN_F == HID_F
static constexpr int kFO = 128;   // OUT_F

// ---------------- scatter-add (mean-agg numerator + counts) ----------------
// one 64-lane sub-wave per edge; lane i handles float4 chunk i of the 256-f row
__global__ __launch_bounds__(256) void k_scatter(
    const float* __restrict__ h, const int* __restrict__ src,
    const int* __restrict__ dst, float* __restrict__ agg,
    int* __restrict__ cnt, int E)
{
    int e = blockIdx.x * 4 + (threadIdx.x >> 6);
    if (e >= E) return;
    int lane = threadIdx.x & 63;
    int s = src[e];
    int d = dst[e];
    float4 v = reinterpret_cast<const float4*>(h + (size_t)s * kF)[lane];
    float* a = agg + (size_t)d * kF + (size_t)lane * 4;
    unsafeAtomicAdd(a + 0, v.x);
    unsafeAtomicAdd(a + 1, v.y);
    unsafeAtomicAdd(a + 2, v.z);
    unsafeAtomicAdd(a + 3, v.w);
    if (lane == 0) atomicAdd(cnt + d, 1);
}

// ---------------- row normalize: agg[r,:] *= 1/max(cnt[r],1) ----------------
__global__ __launch_bounds__(256) void k_normalize(
    float* __restrict__ agg, const int* __restrict__ cnt, int M)
{
    int r = blockIdx.x * 4 + (threadIdx.x >> 6);
    if (r >= M) return;
    int lane = threadIdx.x & 63;
    int c = cnt[r];
    float inv = 1.0f / (float)(c > 1 ? c : 1);
    float4* a = reinterpret_cast<float4*>(agg + (size_t)r * kF);
    float4 v = a[lane];
    v.x *= inv; v.y *= inv; v.z *= inv; v.w *= inv;
    a[lane] = v;
}

// ---------------- fused dual GEMM + bias (+ReLU) ----------------
// out[r,c] = act( sum_k As[r,k]*Ws[k,c] + An[r,k]*Wn[k,c] + b[c] )
// K = 256 fixed. BM=64, BN=128, BK=16. 256 threads, 4x8 outputs/thread.
template <int ACT>
__global__ __launch_bounds__(256) void k_sage_gemm(
    const float* __restrict__ Aself, const float* __restrict__ Aneigh,
    const float* __restrict__ Ws, const float* __restrict__ Wn,
    const float* __restrict__ bias, float* __restrict__ out,
    int M, int N)
{
    const int BM = 64, BN = 128, BK = 16;
    __shared__ float sAs[BK][BM + 4];
    __shared__ float sAn[BK][BM + 4];
    __shared__ float sBs[BK][BN];
    __shared__ float sBn[BK][BN];

    const int tid = threadIdx.x;
    const int tx = tid & 15;    // 16 col groups * 8 cols
    const int ty = tid >> 4;    // 16 row groups * 4 rows
    const int row0 = blockIdx.x * BM;
    const int col0 = blockIdx.y * BN;

    float acc[4][8];
#pragma unroll
    for (int i = 0; i < 4; ++i)
#pragma unroll
        for (int j = 0; j < 8; ++j) acc[i][j] = 0.f;

    // A-load mapping: one float4 per thread per tile (BM*BK/4 = 256)
    const int ar = tid >> 2;          // 64 rows
    const int ak = (tid & 3) * 4;     // 4 float4 chunks of BK=16
    // B-load mapping: 2 float4 per thread (BK*BN/4 = 512)
    for (int k0 = 0; k0 < 256; k0 += BK) {
        {
            int row = row0 + ar;
            float4 vs = make_float4(0.f, 0.f, 0.f, 0.f), vn = vs;
            if (row < M) {
                vs = *reinterpret_cast<const float4*>(Aself + (size_t)row * kF + k0 + ak);
                vn = *reinterpret_cast<const float4*>(Aneigh + (size_t)row * kF + k0 + ak);
            }
            sAs[ak + 0][ar] = vs.x; sAs[ak + 1][ar] = vs.y;
            sAs[ak + 2][ar] = vs.z; sAs[ak + 3][ar] = vs.w;
            sAn[ak + 0][ar] = vn.x; sAn[ak + 1][ar] = vn.y;
            sAn[ak + 2][ar] = vn.z; sAn[ak + 3][ar] = vn.w;
        }
#pragma unroll
        for (int i = 0; i < 2; ++i) {
            int idx = tid + i * 256;          // over 512 float4 slots
            int k = idx >> 5;                 // 16 k's
            int c = (idx & 31) * 4;           // 128 cols
            float4 vs = *reinterpret_cast<const float4*>(Ws + (size_t)(k0 + k) * N + col0 + c);
            float4 vn = *reinterpret_cast<const float4*>(Wn + (size_t)(k0 + k) * N + col0 + c);
            *reinterpret_cast<float4*>(&sBs[k][c]) = vs;
            *reinterpret_cast<float4*>(&sBn[k][c]) = vn;
        }
        __syncthreads();
#pragma unroll
        for (int k = 0; k < BK; ++k) {
            float4 a_s = *reinterpret_cast<const float4*>(&sAs[k][ty * 4]);
            float4 a_n = *reinterpret_cast<const float4*>(&sAn[k][ty * 4]);
            float4 bs0 = *reinterpret_cast<const float4*>(&sBs[k][tx * 8]);
            float4 bs1 = *reinterpret_cast<const float4*>(&sBs[k][tx * 8 + 4]);
            float4 bn0 = *reinterpret_cast<const float4*>(&sBn[k][tx * 8]);
            float4 bn1 = *reinterpret_cast<const float4*>(&sBn[k][tx * 8 + 4]);
            float as_[4] = {a_s.x, a_s.y, a_s.z, a_s.w};
            float an_[4] = {a_n.x, a_n.y, a_n.z, a_n.w};
            float bs_[8] = {bs0.x, bs0.y, bs0.z, bs0.w, bs1.x, bs1.y, bs1.z, bs1.w};
            float bn_[8] = {bn0.x, bn0.y, bn0.z, bn0.w, bn1.x, bn1.y, bn1.z, bn1.w};
#pragma unroll
            for (int i = 0; i < 4; ++i)
#pragma unroll
                for (int j = 0; j < 8; ++j)
                    acc[i][j] += as_[i] * bs_[j] + an_[i] * bn_[j];
        }
        __syncthreads();
    }

    const int orow = row0 + ty * 4;
    const int ocol = col0 + tx * 8;
    float b[8];
#pragma unroll
    for (int j = 0; j < 8; ++j) b[j] = bias[ocol + j];
#pragma unroll
    for (int i = 0; i < 4; ++i) {
        int r = orow + i;
        if (r < M) {
            float v[8];
#pragma unroll
            for (int j = 0; j < 8; ++j) {
                v[j] = acc[i][j] + b[j];
                if (ACT) v[j] = fmaxf(v[j], 0.f);
            }
            float* op = out + (size_t)r * N + ocol;
            reinterpret_cast<float4*>(op)[0] = make_float4(v[0], v[1], v[2], v[3]);
            reinterpret_cast<float4*>(op)[1] = make_float4(v[4], v[5], v[6], v[7]);
        }
    }
}

extern "C" void kernel_launch(void* const* d_in, const int* in_sizes, int n_in,
                              void* d_out, int out_size, void* d_ws, size_t ws_size,
                              hipStream_t stream) {
    const float* feat = (const float*)d_in[0];
    const int* e0s = (const int*)d_in[1];
    const int* e0d = (const int*)d_in[2];
    const int* e1s = (const int*)d_in[3];
    const int* e1d = (const int*)d_in[4];
    const int* e2s = (const int*)d_in[5];
    const int* e2d = (const int*)d_in[6];
    const float* ws0 = (const float*)d_in[7];
    const float* wn0 = (const float*)d_in[8];
    const float* b0 = (const float*)d_in[9];
    const float* ws1 = (const float*)d_in[10];
    const float* wn1 = (const float*)d_in[11];
    const float* b1 = (const float*)d_in[12];
    const float* ws2 = (const float*)d_in[13];
    const float* wn2 = (const float*)d_in[14];
    const float* b2 = (const float*)d_in[15];
    float* out = (float*)d_out;

    // workspace layout (floats): agg 25.6M | h1 25.6M | h2 5.12M | cnt 100K ints
    // total ~225.7 MB
    float* agg = (float*)d_ws;
    float* h1 = agg + 25600000ull;
    float* h2 = h1 + 25600000ull;
    int* cnt = (int*)(h2 + 5120000ull);

    // ---- layer 0: feat[N0] --(E0)--> h1[N1], ReLU ----
    hipMemsetAsync(agg, 0, (size_t)kN1 * kF * 4, stream);
    hipMemsetAsync(cnt, 0, (size_t)kN1 * 4, stream);
    k_scatter<<<(kE0 + 3) / 4, 256, 0, stream>>>(feat, e0s, e0d, agg, cnt, kE0);
    k_normalize<<<(kN1 + 3) / 4, 256, 0, stream>>>(agg, cnt, kN1);
    k_sage_gemm<1><<<dim3((kN1 + 63) / 64, 2), 256, 0, stream>>>(
        feat, agg, ws0, wn0, b0, h1, kN1, kF);

    // ---- layer 1: h1[N1] --(E1)--> h2[N2], ReLU ----
    hipMemsetAsync(agg, 0, (size_t)kN2 * kF * 4, stream);
    hipMemsetAsync(cnt, 0, (size_t)kN2 * 4, stream);
    k_scatter<<<(kE1 + 3) / 4, 256, 0, stream>>>(h1, e1s, e1d, agg, cnt, kE1);
    k_normalize<<<(kN2 + 3) / 4, 256, 0, stream>>>(agg, cnt, kN2);
    k_sage_gemm<1><<<dim3((kN2 + 63) / 64, 2), 256, 0, stream>>>(
        h1, agg, ws1, wn1, b1, h2, kN2, kF);

    // ---- layer 2: h2[N2] --(E2)--> out[N3], no act ----
    hipMemsetAsync(agg, 0, (size_t)kN3 * kF * 4, stream);
    hipMemsetAsync(cnt, 0, (size_t)kN3 * 4, stream);
    k_scatter<<<(kE2 + 3) / 4, 256, 0, stream>>>(h2, e2s, e2d, agg, cnt, kE2);
    k_normalize<<<(kN3 + 3) / 4, 256, 0, stream>>>(agg, cnt, kN3);
    k_sage_gemm<0><<<dim3((kN3 + 63) / 64, 1), 256, 0, stream>>>(
        h2, agg, ws2, wn2, b2, out, kN3, kFO);
}

// Round 2
// 1771.136 us; speedup vs baseline: 4.0325x; 4.0325x over previous
//
#include <hip/hip_runtime.h>

// GraphSAGE 3-layer, eval mode. All fp32.
// N0=400000, N1=100000, N2=20000, N3=4096; F=256 (in/hid), 128 out
// E0=1.5M, E1=200K, E2=40960
//
// Aggregation strategy: device-built CSR (count -> scan -> fill) then
// gather-based segment mean (one 64-lane wave per dst row). Replaces the
// round-1 float atomic scatter that wrote 6 GB through L2 (WRITE_SIZE).

static constexpr int kN1 = 100000;
static constexpr int kN2 = 20000;
static constexpr int kN3 = 4096;
static constexpr int kE0 = 1500000;
static constexpr int kE1 = 200000;
static constexpr int kE2 = 40960;
static constexpr int kF  = 256;   // IN_F == HID_F
static constexpr int kFO = 128;   // OUT_F

// ---------------- CSR build: count ----------------
__global__ __launch_bounds__(256) void k_count(
    const int* __restrict__ dst, int* __restrict__ cnt, int E)
{
    int e = blockIdx.x * 256 + threadIdx.x;
    if (e < E) atomicAdd(cnt + dst[e], 1);
}

// ---------------- CSR build: exclusive scan (single block, 1024 thr) ----------------
// rp[i] = sum(cnt[0..i-1])  (exclusive start offsets)
__global__ __launch_bounds__(1024) void k_scan(
    const int* __restrict__ cnt, int* __restrict__ rp, int M)
{
    __shared__ int wsum[16];
    const int lane = threadIdx.x & 63;
    const int wid = threadIdx.x >> 6;
    int carry = 0;  // uniform across threads
    for (int base = 0; base < M; base += 1024) {
        int i = base + threadIdx.x;
        int v = (i < M) ? cnt[i] : 0;
        // wave-inclusive scan
        int vs = v;
#pragma unroll
        for (int off = 1; off < 64; off <<= 1) {
            int t = __shfl_up(vs, off, 64);
            if (lane >= off) vs += t;
        }
        if (lane == 63) wsum[wid] = vs;
        __syncthreads();
        if (threadIdx.x < 16) {
            int wv = wsum[threadIdx.x];
#pragma unroll
            for (int off = 1; off < 16; off <<= 1) {
                int t = __shfl_up(wv, off, 16);
                if (threadIdx.x >= off) wv += t;
            }
            wsum[threadIdx.x] = wv;  // inclusive over waves
        }
        __syncthreads();
        int block_excl = (wid > 0 ? wsum[wid - 1] : 0) + (vs - v);
        if (i < M) rp[i] = carry + block_excl;
        carry += wsum[15];
        __syncthreads();  // protect wsum before next tile
    }
}

// ---------------- CSR build: fill (rp becomes end-offsets afterwards) ----------------
__global__ __launch_bounds__(256) void k_fill(
    const int* __restrict__ src, const int* __restrict__ dst,
    int* __restrict__ rp, int* __restrict__ csr, int E)
{
    int e = blockIdx.x * 256 + threadIdx.x;
    if (e < E) {
        int pos = atomicAdd(rp + dst[e], 1);
        csr[pos] = src[e];
    }
}

// ---------------- gather-based segment mean ----------------
// one wave per dst row; lane l owns float4 chunk l of the 256-f row.
// rp_end[d] = end offset, cnt[d] = edge count (start = end - cnt).
__global__ __launch_bounds__(256) void k_gather_agg(
    const float* __restrict__ h, const int* __restrict__ csr,
    const int* __restrict__ rp_end, const int* __restrict__ cnt,
    float* __restrict__ agg, int M)
{
    int d = blockIdx.x * 4 + (threadIdx.x >> 6);
    if (d >= M) return;
    int lane = threadIdx.x & 63;
    int c = cnt[d];
    int end = rp_end[d];
    int start = end - c;
    float4 acc = make_float4(0.f, 0.f, 0.f, 0.f);
    for (int chunk = start; chunk < end; chunk += 64) {
        int n = end - chunk; if (n > 64) n = 64;
        int mysrc = (lane < n) ? csr[chunk + lane] : 0;
#pragma unroll 4
        for (int e = 0; e < n; ++e) {
            int s = __shfl(mysrc, e, 64);
            float4 v = reinterpret_cast<const float4*>(h + (size_t)s * kF)[lane];
            acc.x += v.x; acc.y += v.y; acc.z += v.z; acc.w += v.w;
        }
    }
    float inv = 1.0f / (float)(c > 1 ? c : 1);
    acc.x *= inv; acc.y *= inv; acc.z *= inv; acc.w *= inv;
    reinterpret_cast<float4*>(agg + (size_t)d * kF)[lane] = acc;
}

// ---------------- fused dual GEMM + bias (+ReLU) ----------------
// out[r,c] = act( sum_k As[r,k]*Ws[k,c] + An[r,k]*Wn[k,c] + b[c] )
// K = 256 fixed. BM=64, BN=128, BK=16. 256 threads, 4x8 outputs/thread.
template <int ACT>
__global__ __launch_bounds__(256) void k_sage_gemm(
    const float* __restrict__ Aself, const float* __restrict__ Aneigh,
    const float* __restrict__ Ws, const float* __restrict__ Wn,
    const float* __restrict__ bias, float* __restrict__ out,
    int M, int N)
{
    const int BM = 64, BN = 128, BK = 16;
    __shared__ float sAs[BK][BM + 4];
    __shared__ float sAn[BK][BM + 4];
    __shared__ float sBs[BK][BN];
    __shared__ float sBn[BK][BN];

    const int tid = threadIdx.x;
    const int tx = tid & 15;    // 16 col groups * 8 cols
    const int ty = tid >> 4;    // 16 row groups * 4 rows
    const int row0 = blockIdx.x * BM;
    const int col0 = blockIdx.y * BN;

    float acc[4][8];
#pragma unroll
    for (int i = 0; i < 4; ++i)
#pragma unroll
        for (int j = 0; j < 8; ++j) acc[i][j] = 0.f;

    const int ar = tid >> 2;          // 64 rows
    const int ak = (tid & 3) * 4;     // 4 float4 chunks of BK=16
    for (int k0 = 0; k0 < 256; k0 += BK) {
        {
            int row = row0 + ar;
            float4 vs = make_float4(0.f, 0.f, 0.f, 0.f), vn = vs;
            if (row < M) {
                vs = *reinterpret_cast<const float4*>(Aself + (size_t)row * kF + k0 + ak);
                vn = *reinterpret_cast<const float4*>(Aneigh + (size_t)row * kF + k0 + ak);
            }
            sAs[ak + 0][ar] = vs.x; sAs[ak + 1][ar] = vs.y;
            sAs[ak + 2][ar] = vs.z; sAs[ak + 3][ar] = vs.w;
            sAn[ak + 0][ar] = vn.x; sAn[ak + 1][ar] = vn.y;
            sAn[ak + 2][ar] = vn.z; sAn[ak + 3][ar] = vn.w;
        }
#pragma unroll
        for (int i = 0; i < 2; ++i) {
            int idx = tid + i * 256;          // over 512 float4 slots
            int k = idx >> 5;                 // 16 k's
            int c = (idx & 31) * 4;           // 128 cols
            float4 vs = *reinterpret_cast<const float4*>(Ws + (size_t)(k0 + k) * N + col0 + c);
            float4 vn = *reinterpret_cast<const float4*>(Wn + (size_t)(k0 + k) * N + col0 + c);
            *reinterpret_cast<float4*>(&sBs[k][c]) = vs;
            *reinterpret_cast<float4*>(&sBn[k][c]) = vn;
        }
        __syncthreads();
#pragma unroll
        for (int k = 0; k < BK; ++k) {
            float4 a_s = *reinterpret_cast<const float4*>(&sAs[k][ty * 4]);
            float4 a_n = *reinterpret_cast<const float4*>(&sAn[k][ty * 4]);
            float4 bs0 = *reinterpret_cast<const float4*>(&sBs[k][tx * 8]);
            float4 bs1 = *reinterpret_cast<const float4*>(&sBs[k][tx * 8 + 4]);
            float4 bn0 = *reinterpret_cast<const float4*>(&sBn[k][tx * 8]);
            float4 bn1 = *reinterpret_cast<const float4*>(&sBn[k][tx * 8 + 4]);
            float as_[4] = {a_s.x, a_s.y, a_s.z, a_s.w};
            float an_[4] = {a_n.x, a_n.y, a_n.z, a_n.w};
            float bs_[8] = {bs0.x, bs0.y, bs0.z, bs0.w, bs1.x, bs1.y, bs1.z, bs1.w};
            float bn_[8] = {bn0.x, bn0.y, bn0.z, bn0.w, bn1.x, bn1.y, bn1.z, bn1.w};
#pragma unroll
            for (int i = 0; i < 4; ++i)
#pragma unroll
                for (int j = 0; j < 8; ++j)
                    acc[i][j] += as_[i] * bs_[j] + an_[i] * bn_[j];
        }
        __syncthreads();
    }

    const int orow = row0 + ty * 4;
    const int ocol = col0 + tx * 8;
    float b[8];
#pragma unroll
    for (int j = 0; j < 8; ++j) b[j] = bias[ocol + j];
#pragma unroll
    for (int i = 0; i < 4; ++i) {
        int r = orow + i;
        if (r < M) {
            float v[8];
#pragma unroll
            for (int j = 0; j < 8; ++j) {
                v[j] = acc[i][j] + b[j];
                if (ACT) v[j] = fmaxf(v[j], 0.f);
            }
            float* op = out + (size_t)r * N + ocol;
            reinterpret_cast<float4*>(op)[0] = make_float4(v[0], v[1], v[2], v[3]);
            reinterpret_cast<float4*>(op)[1] = make_float4(v[4], v[5], v[6], v[7]);
        }
    }
}

extern "C" void kernel_launch(void* const* d_in, const int* in_sizes, int n_in,
                              void* d_out, int out_size, void* d_ws, size_t ws_size,
                              hipStream_t stream) {
    const float* feat = (const float*)d_in[0];
    const int* e0s = (const int*)d_in[1];
    const int* e0d = (const int*)d_in[2];
    const int* e1s = (const int*)d_in[3];
    const int* e1d = (const int*)d_in[4];
    const int* e2s = (const int*)d_in[5];
    const int* e2d = (const int*)d_in[6];
    const float* ws0 = (const float*)d_in[7];
    const float* wn0 = (const float*)d_in[8];
    const float* b0 = (const float*)d_in[9];
    const float* ws1 = (const float*)d_in[10];
    const float* wn1 = (const float*)d_in[11];
    const float* b1 = (const float*)d_in[12];
    const float* ws2 = (const float*)d_in[13];
    const float* wn2 = (const float*)d_in[14];
    const float* b2 = (const float*)d_in[15];
    float* out = (float*)d_out;

    // workspace layout (floats):
    //   agg region: 25.6M floats (102.4 MB)
    //     - layer0 agg: rows 0..N1      (full region)
    //     - layer1 agg: rows 0..N2      (first 5.12M floats)
    //     - h2: at agg + 12.8M floats   (N2*256 = 5.12M floats; no overlap)
    //     - layer2 agg: rows 0..N3      (first 1.05M floats; no overlap w/ h2)
    //   h1: 25.6M floats (102.4 MB)
    //   csr: 1.5M ints | cnt: 100K ints | rp: 100K ints
    // total ~= 216.5 MB
    float* agg = (float*)d_ws;
    float* h1 = agg + 25600000ull;
    float* h2 = agg + 12800000ull;
    int* csr = (int*)(h1 + 25600000ull);
    int* cnt = csr + 1500000;
    int* rp = cnt + 100000;

    // ---- layer 0: feat[N0] --(E0)--> h1[N1], ReLU ----
    hipMemsetAsync(cnt, 0, (size_t)kN1 * 4, stream);
    k_count<<<(kE0 + 255) / 256, 256, 0, stream>>>(e0d, cnt, kE0);
    k_scan<<<1, 1024, 0, stream>>>(cnt, rp, kN1);
    k_fill<<<(kE0 + 255) / 256, 256, 0, stream>>>(e0s, e0d, rp, csr, kE0);
    k_gather_agg<<<(kN1 + 3) / 4, 256, 0, stream>>>(feat, csr, rp, cnt, agg, kN1);
    k_sage_gemm<1><<<dim3((kN1 + 63) / 64, 2), 256, 0, stream>>>(
        feat, agg, ws0, wn0, b0, h1, kN1, kF);

    // ---- layer 1: h1[N1] --(E1)--> h2[N2], ReLU ----
    hipMemsetAsync(cnt, 0, (size_t)kN2 * 4, stream);
    k_count<<<(kE1 + 255) / 256, 256, 0, stream>>>(e1d, cnt, kE1);
    k_scan<<<1, 1024, 0, stream>>>(cnt, rp, kN2);
    k_fill<<<(kE1 + 255) / 256, 256, 0, stream>>>(e1s, e1d, rp, csr, kE1);
    k_gather_agg<<<(kN2 + 3) / 4, 256, 0, stream>>>(h1, csr, rp, cnt, agg, kN2);
    k_sage_gemm<1><<<dim3((kN2 + 63) / 64, 2), 256, 0, stream>>>(
        h1, agg, ws1, wn1, b1, h2, kN2, kF);

    // ---- layer 2: h2[N2] --(E2)--> out[N3], no act ----
    hipMemsetAsync(cnt, 0, (size_t)kN3 * 4, stream);
    k_count<<<(kE2 + 255) / 256, 256, 0, stream>>>(e2d, cnt, kE2);
    k_scan<<<1, 1024, 0, stream>>>(cnt, rp, kN3);
    k_fill<<<(kE2 + 255) / 256, 256, 0, stream>>>(e2s, e2d, rp, csr, kE2);
    k_gather_agg<<<(kN3 + 3) / 4, 256, 0, stream>>>(h2, csr, rp, cnt, agg, kN3);
    k_sage_gemm<0><<<dim3((kN3 + 63) / 64, 1), 256, 0, stream>>>(
        h2, agg, ws2, wn2, b2, out, kN3, kFO);
}

// Round 3
// 731.016 us; speedup vs baseline: 9.7702x; 2.4228x over previous
//
#include <hip/hip_runtime.h>
#include <hip/hip_bf16.h>

// GraphSAGE 3-layer, eval mode.
// Round 3: bf16 MFMA GEMM (v_mfma_f32_16x16x32_bf16), bf16 intermediates,
// CSR gather aggregation. Optional bf16 feat copy if workspace allows
// (fits the 256 MB L3 -> faster layer-0 gather).

static constexpr int kN1 = 100000, kN2 = 20000, kN3 = 4096;
static constexpr int kE0 = 1500000, kE1 = 200000, kE2 = 40960;

using bf8v  = __attribute__((ext_vector_type(8))) short;   // 8 bf16 (4 VGPR)
using f32x4 = __attribute__((ext_vector_type(4))) float;   // MFMA acc

__device__ __forceinline__ unsigned short f2bu(float f) {
    __hip_bfloat16 h = __float2bfloat16(f);
    return *reinterpret_cast<unsigned short*>(&h);
}
__device__ __forceinline__ float bu2f_lo(unsigned u) {
    unsigned b = u << 16; return *reinterpret_cast<float*>(&b);
}
__device__ __forceinline__ float bu2f_hi(unsigned u) {
    unsigned b = u & 0xffff0000u; return *reinterpret_cast<float*>(&b);
}

// ---------------- CSR build ----------------
__global__ __launch_bounds__(256) void k_count(
    const int* __restrict__ dst, int* __restrict__ cnt, int E)
{
    int e = blockIdx.x * 256 + threadIdx.x;
    if (e < E) atomicAdd(cnt + dst[e], 1);
}

__global__ __launch_bounds__(1024) void k_scan(
    const int* __restrict__ cnt, int* __restrict__ rp, int M)
{
    __shared__ int wsum[16];
    const int lane = threadIdx.x & 63;
    const int wid = threadIdx.x >> 6;
    int carry = 0;
    for (int base = 0; base < M; base += 1024) {
        int i = base + threadIdx.x;
        int v = (i < M) ? cnt[i] : 0;
        int vs = v;
#pragma unroll
        for (int off = 1; off < 64; off <<= 1) {
            int t = __shfl_up(vs, off, 64);
            if (lane >= off) vs += t;
        }
        if (lane == 63) wsum[wid] = vs;
        __syncthreads();
        if (threadIdx.x < 16) {
            int wv = wsum[threadIdx.x];
#pragma unroll
            for (int off = 1; off < 16; off <<= 1) {
                int t = __shfl_up(wv, off, 16);
                if (threadIdx.x >= off) wv += t;
            }
            wsum[threadIdx.x] = wv;
        }
        __syncthreads();
        int block_excl = (wid > 0 ? wsum[wid - 1] : 0) + (vs - v);
        if (i < M) rp[i] = carry + block_excl;
        carry += wsum[15];
        __syncthreads();
    }
}

__global__ __launch_bounds__(256) void k_fill(
    const int* __restrict__ src, const int* __restrict__ dst,
    int* __restrict__ rp, int* __restrict__ csr, int E)
{
    int e = blockIdx.x * 256 + threadIdx.x;
    if (e < E) {
        int pos = atomicAdd(rp + dst[e], 1);
        csr[pos] = src[e];
    }
}

// ---------------- gather segment-mean -> bf16 ----------------
// one wave per dst row; lane owns 4 features. INF32: src rows are f32.
template <bool INF32>
__global__ __launch_bounds__(256) void k_gather_agg(
    const void* __restrict__ hv, const int* __restrict__ csr,
    const int* __restrict__ rp_end, const int* __restrict__ cnt,
    unsigned short* __restrict__ agg, int M)
{
    int d = blockIdx.x * 4 + (threadIdx.x >> 6);
    if (d >= M) return;
    int lane = threadIdx.x & 63;
    int c = cnt[d], end = rp_end[d], start = end - c;
    float a0 = 0.f, a1 = 0.f, a2 = 0.f, a3 = 0.f;
    for (int chunk = start; chunk < end; chunk += 64) {
        int n = end - chunk; if (n > 64) n = 64;
        int mysrc = (lane < n) ? csr[chunk + lane] : 0;
        for (int e = 0; e < n; ++e) {
            int s = __shfl(mysrc, e, 64);
            if constexpr (INF32) {
                float4 v = reinterpret_cast<const float4*>(
                    (const float*)hv + (size_t)s * 256)[lane];
                a0 += v.x; a1 += v.y; a2 += v.z; a3 += v.w;
            } else {
                uint2 v = reinterpret_cast<const uint2*>(
                    (const unsigned short*)hv + (size_t)s * 256)[lane];
                a0 += bu2f_lo(v.x); a1 += bu2f_hi(v.x);
                a2 += bu2f_lo(v.y); a3 += bu2f_hi(v.y);
            }
        }
    }
    float inv = 1.0f / (float)(c > 1 ? c : 1);
    ushort4 o;
    o.x = f2bu(a0 * inv); o.y = f2bu(a1 * inv);
    o.z = f2bu(a2 * inv); o.w = f2bu(a3 * inv);
    *reinterpret_cast<ushort4*>(agg + (size_t)d * 256 + lane * 4) = o;
}

// ---------------- weight prep: WT[n][k] bf16, k<256 self / k>=256 neigh ----
__global__ __launch_bounds__(256) void k_prep_wt(
    const float* __restrict__ Ws, const float* __restrict__ Wn,
    unsigned short* __restrict__ WT, int N)
{
    int idx = blockIdx.x * 256 + threadIdx.x;
    if (idx >= N * 512) return;
    int n = idx >> 9, k = idx & 511;
    float v = (k < 256) ? Ws[k * N + n] : Wn[(k - 256) * N + n];
    WT[idx] = f2bu(v);
}

// ---------------- cast f32 -> bf16 (8 elems/thread) ----------------
__global__ __launch_bounds__(256) void k_cast_f2b(
    const float4* __restrict__ in, uint4* __restrict__ out, int nOct)
{
    int i = blockIdx.x * 256 + threadIdx.x;
    if (i >= nOct) return;
    float4 a = in[2 * i], b = in[2 * i + 1];
    uint4 o;
    o.x = (unsigned)f2bu(a.x) | ((unsigned)f2bu(a.y) << 16);
    o.y = (unsigned)f2bu(a.z) | ((unsigned)f2bu(a.w) << 16);
    o.z = (unsigned)f2bu(b.x) | ((unsigned)f2bu(b.y) << 16);
    o.w = (unsigned)f2bu(b.z) | ((unsigned)f2bu(b.w) << 16);
    out[i] = o;
}

// ---------------- MFMA dual-GEMM: out = act([A0|A1] @ WT^T + b) ----------------
// K = 512 (k<256 from A0, k>=256 from A1). BM=BN=128, BK=64.
// 4 waves, each 64x64 sub-tile = 4x4 frags of 16x16x32 bf16 MFMA.
// LDS pitch 72 bf16 (144 B) -> <=2-way bank aliasing on ds_read_b128 (free).
template <int ACT, bool A0F32, bool OUTF32>
__global__ __launch_bounds__(256) void k_mfma_gemm(
    const void* __restrict__ A0v, const unsigned short* __restrict__ A1,
    const unsigned short* __restrict__ WT, const float* __restrict__ bias,
    void* __restrict__ outv, int M, int N)
{
    __shared__ unsigned short sA[128 * 72];
    __shared__ unsigned short sB[128 * 72];
    const int tid = threadIdx.x;
    const int lane = tid & 63;
    const int w = tid >> 6;
    const int wr = w >> 1, wc = w & 1;
    const int row0 = blockIdx.x * 128;
    const int col0 = blockIdx.y * 128;

    f32x4 acc[4][4] = {};

    for (int p = 0; p < 8; ++p) {
        const int kc0 = p * 64;
        // ---- stage A (128 x 64 bf16) ----
        if (kc0 < 256) {
            if constexpr (A0F32) {
                const float* src = (const float*)A0v;
#pragma unroll
                for (int ps = 0; ps < 8; ++ps) {
                    int flat = (ps * 256 + tid) * 4;
                    int r = flat >> 6, cc = flat & 63;
                    int row = row0 + r; row = row < M ? row : M - 1;
                    float4 v = *reinterpret_cast<const float4*>(
                        src + (size_t)row * 256 + kc0 + cc);
                    ushort4 b4;
                    b4.x = f2bu(v.x); b4.y = f2bu(v.y);
                    b4.z = f2bu(v.z); b4.w = f2bu(v.w);
                    *reinterpret_cast<ushort4*>(&sA[r * 72 + cc]) = b4;
                }
            } else {
                const unsigned short* src = (const unsigned short*)A0v;
#pragma unroll
                for (int ps = 0; ps < 4; ++ps) {
                    int f8 = ps * 256 + tid;
                    int r = f8 >> 3, c8 = f8 & 7;
                    int row = row0 + r; row = row < M ? row : M - 1;
                    uint4 v = *reinterpret_cast<const uint4*>(
                        src + (size_t)row * 256 + kc0 + c8 * 8);
                    *reinterpret_cast<uint4*>(&sA[r * 72 + c8 * 8]) = v;
                }
            }
        } else {
#pragma unroll
            for (int ps = 0; ps < 4; ++ps) {
                int f8 = ps * 256 + tid;
                int r = f8 >> 3, c8 = f8 & 7;
                int row = row0 + r; row = row < M ? row : M - 1;
                uint4 v = *reinterpret_cast<const uint4*>(
                    A1 + (size_t)row * 256 + (kc0 - 256) + c8 * 8);
                *reinterpret_cast<uint4*>(&sA[r * 72 + c8 * 8]) = v;
            }
        }
        // ---- stage B: WT rows (N-cols) x 64 k ----
#pragma unroll
        for (int ps = 0; ps < 4; ++ps) {
            int f8 = ps * 256 + tid;
            int r = f8 >> 3, c8 = f8 & 7;
            uint4 v = *reinterpret_cast<const uint4*>(
                WT + (size_t)(col0 + r) * 512 + kc0 + c8 * 8);
            *reinterpret_cast<uint4*>(&sB[r * 72 + c8 * 8]) = v;
        }
        __syncthreads();
        // ---- compute: 2 k-steps of 32 ----
#pragma unroll
        for (int ks = 0; ks < 64; ks += 32) {
            const int lr = lane & 15;
            const int kk = ks + (lane >> 4) * 8;
            bf8v af[4], bfr[4];
#pragma unroll
            for (int m = 0; m < 4; ++m)
                af[m] = *reinterpret_cast<const bf8v*>(
                    &sA[(wr * 64 + m * 16 + lr) * 72 + kk]);
#pragma unroll
            for (int n = 0; n < 4; ++n)
                bfr[n] = *reinterpret_cast<const bf8v*>(
                    &sB[(wc * 64 + n * 16 + lr) * 72 + kk]);
#pragma unroll
            for (int m = 0; m < 4; ++m)
#pragma unroll
                for (int n = 0; n < 4; ++n)
                    acc[m][n] = __builtin_amdgcn_mfma_f32_16x16x32_bf16(
                        af[m], bfr[n], acc[m][n], 0, 0, 0);
        }
        __syncthreads();
    }

    // ---- epilogue: C/D layout col=lane&15, row=(lane>>4)*4+j ----
    const int lc = lane & 15;
    const int lr4 = (lane >> 4) * 4;
#pragma unroll
    for (int n = 0; n < 4; ++n) {
        int col = col0 + wc * 64 + n * 16 + lc;
        float bb = bias[col];
#pragma unroll
        for (int m = 0; m < 4; ++m) {
#pragma unroll
            for (int j = 0; j < 4; ++j) {
                int row = row0 + wr * 64 + m * 16 + lr4 + j;
                if (row < M) {
                    float v = acc[m][n][j] + bb;
                    if (ACT) v = fmaxf(v, 0.f);
                    if constexpr (OUTF32)
                        ((float*)outv)[(size_t)row * N + col] = v;
                    else
                        ((unsigned short*)outv)[(size_t)row * N + col] = f2bu(v);
                }
            }
        }
    }
}

extern "C" void kernel_launch(void* const* d_in, const int* in_sizes, int n_in,
                              void* d_out, int out_size, void* d_ws, size_t ws_size,
                              hipStream_t stream) {
    const float* feat = (const float*)d_in[0];
    const int* e0s = (const int*)d_in[1];
    const int* e0d = (const int*)d_in[2];
    const int* e1s = (const int*)d_in[3];
    const int* e1d = (const int*)d_in[4];
    const int* e2s = (const int*)d_in[5];
    const int* e2d = (const int*)d_in[6];
    const float* ws0 = (const float*)d_in[7];
    const float* wn0 = (const float*)d_in[8];
    const float* b0 = (const float*)d_in[9];
    const float* ws1 = (const float*)d_in[10];
    const float* wn1 = (const float*)d_in[11];
    const float* b1 = (const float*)d_in[12];
    const float* ws2 = (const float*)d_in[13];
    const float* wn2 = (const float*)d_in[14];
    const float* b2 = (const float*)d_in[15];
    float* out = (float*)d_out;

    // workspace layout (bytes):
    //  big (>=~325MB): featbf 204.8M | aggb 51.2M | h1b 51.2M | h2b 10.24M |
    //                  wt0/wt1/wt2 | csr 6M | cnt 0.4M | rp 0.4M
    //  small: same minus featbf (~120MB)
    char* base = (char*)d_ws;
    const bool big = ws_size >= 324900000ull;
    unsigned short* featbf = nullptr;
    size_t off = 0;
    if (big) { featbf = (unsigned short*)base; off += 204800000ull; }
    unsigned short* aggb = (unsigned short*)(base + off); off += 51200000ull;
    unsigned short* h1b  = (unsigned short*)(base + off); off += 51200000ull;
    unsigned short* h2b  = (unsigned short*)(base + off); off += 10240000ull;
    unsigned short* wt0  = (unsigned short*)(base + off); off += 262144ull;
    unsigned short* wt1  = (unsigned short*)(base + off); off += 262144ull;
    unsigned short* wt2  = (unsigned short*)(base + off); off += 131072ull;
    int* csr = (int*)(base + off); off += 6000000ull;
    int* cnt = (int*)(base + off); off += 400000ull;
    int* rp  = (int*)(base + off); off += 400000ull;

    // weight prep + optional feat cast
    k_prep_wt<<<512, 256, 0, stream>>>(ws0, wn0, wt0, 256);
    k_prep_wt<<<512, 256, 0, stream>>>(ws1, wn1, wt1, 256);
    k_prep_wt<<<256, 256, 0, stream>>>(ws2, wn2, wt2, 128);
    if (big)
        k_cast_f2b<<<50000, 256, 0, stream>>>(
            (const float4*)feat, (uint4*)featbf, 12800000);

    // ---- layer 0: feat[400K] --(E0)--> h1b[100K], ReLU ----
    hipMemsetAsync(cnt, 0, (size_t)kN1 * 4, stream);
    k_count<<<(kE0 + 255) / 256, 256, 0, stream>>>(e0d, cnt, kE0);
    k_scan<<<1, 1024, 0, stream>>>(cnt, rp, kN1);
    k_fill<<<(kE0 + 255) / 256, 256, 0, stream>>>(e0s, e0d, rp, csr, kE0);
    if (big) {
        k_gather_agg<false><<<(kN1 + 3) / 4, 256, 0, stream>>>(
            featbf, csr, rp, cnt, aggb, kN1);
        k_mfma_gemm<1, false, false><<<dim3(782, 2), 256, 0, stream>>>(
            featbf, aggb, wt0, b0, h1b, kN1, 256);
    } else {
        k_gather_agg<true><<<(kN1 + 3) / 4, 256, 0, stream>>>(
            feat, csr, rp, cnt, aggb, kN1);
        k_mfma_gemm<1, true, false><<<dim3(782, 2), 256, 0, stream>>>(
            feat, aggb, wt0, b0, h1b, kN1, 256);
    }

    // ---- layer 1: h1b[100K] --(E1)--> h2b[20K], ReLU ----
    hipMemsetAsync(cnt, 0, (size_t)kN2 * 4, stream);
    k_count<<<(kE1 + 255) / 256, 256, 0, stream>>>(e1d, cnt, kE1);
    k_scan<<<1, 1024, 0, stream>>>(cnt, rp, kN2);
    k_fill<<<(kE1 + 255) / 256, 256, 0, stream>>>(e1s, e1d, rp, csr, kE1);
    k_gather_agg<false><<<(kN2 + 3) / 4, 256, 0, stream>>>(
        h1b, csr, rp, cnt, aggb, kN2);
    k_mfma_gemm<1, false, false><<<dim3(157, 2), 256, 0, stream>>>(
        h1b, aggb, wt1, b1, h2b, kN2, 256);

    // ---- layer 2: h2b[20K] --(E2)--> out[4096], no act, f32 out ----
    hipMemsetAsync(cnt, 0, (size_t)kN3 * 4, stream);
    k_count<<<(kE2 + 255) / 256, 256, 0, stream>>>(e2d, cnt, kE2);
    k_scan<<<1, 1024, 0, stream>>>(cnt, rp, kN3);
    k_fill<<<(kE2 + 255) / 256, 256, 0, stream>>>(e2s, e2d, rp, csr, kE2);
    k_gather_agg<false><<<(kN3 + 3) / 4, 256, 0, stream>>>(
        h2b, csr, rp, cnt, aggb, kN3);
    k_mfma_gemm<0, false, true><<<dim3(32, 1), 256, 0, stream>>>(
        h2b, aggb, wt2, b2, out, kN3, 128);
}

// Round 4
// 639.051 us; speedup vs baseline: 11.1762x; 1.1439x over previous
//
#include <hip/hip_runtime.h>
#include <hip/hip_bf16.h>

// GraphSAGE 3-layer, eval mode.
// Round 4: parallel 3-phase CSR scan (was: single-block serial scan ~125us),
// unrolled gather edge loop. MFMA bf16 GEMM unchanged from round 3.

static constexpr int kN1 = 100000, kN2 = 20000, kN3 = 4096;
static constexpr int kE0 = 1500000, kE1 = 200000, kE2 = 40960;

using bf8v  = __attribute__((ext_vector_type(8))) short;   // 8 bf16 (4 VGPR)
using f32x4 = __attribute__((ext_vector_type(4))) float;   // MFMA acc

__device__ __forceinline__ unsigned short f2bu(float f) {
    __hip_bfloat16 h = __float2bfloat16(f);
    return *reinterpret_cast<unsigned short*>(&h);
}
__device__ __forceinline__ float bu2f_lo(unsigned u) {
    unsigned b = u << 16; return *reinterpret_cast<float*>(&b);
}
__device__ __forceinline__ float bu2f_hi(unsigned u) {
    unsigned b = u & 0xffff0000u; return *reinterpret_cast<float*>(&b);
}

// ---------------- CSR build: count ----------------
__global__ __launch_bounds__(256) void k_count(
    const int* __restrict__ dst, int* __restrict__ cnt, int E)
{
    int e = blockIdx.x * 256 + threadIdx.x;
    if (e < E) atomicAdd(cnt + dst[e], 1);
}

// ---------------- parallel scan, phase 1: per-block (1024 ints) sums --------
__global__ __launch_bounds__(256) void k_bsum(
    const int* __restrict__ cnt, int* __restrict__ bsum, int M4)
{
    __shared__ int wsum[4];
    int idx = blockIdx.x * 256 + threadIdx.x;
    int ts = 0;
    if (idx < M4) {
        int4 v = reinterpret_cast<const int4*>(cnt)[idx];
        ts = v.x + v.y + v.z + v.w;
    }
    // wave reduce
#pragma unroll
    for (int off = 32; off > 0; off >>= 1) ts += __shfl_down(ts, off, 64);
    if ((threadIdx.x & 63) == 0) wsum[threadIdx.x >> 6] = ts;
    __syncthreads();
    if (threadIdx.x == 0)
        bsum[blockIdx.x] = wsum[0] + wsum[1] + wsum[2] + wsum[3];
}

// ---------------- phase 2: exclusive scan of B (<=128) block sums -----------
__global__ __launch_bounds__(256) void k_bscan(int* __restrict__ bsum, int B)
{
    __shared__ int s[128];
    if (threadIdx.x < B) s[threadIdx.x] = bsum[threadIdx.x];
    __syncthreads();
    if (threadIdx.x == 0) {
        int run = 0;
        for (int i = 0; i < B; ++i) { int v = s[i]; s[i] = run; run += v; }
    }
    __syncthreads();
    if (threadIdx.x < B) bsum[threadIdx.x] = s[threadIdx.x];
}

// ---------------- phase 3: apply -> exclusive start offsets rp --------------
__global__ __launch_bounds__(256) void k_bapply(
    const int* __restrict__ cnt, const int* __restrict__ bsum,
    int* __restrict__ rp, int M4)
{
    __shared__ int wsum[4];
    __shared__ int wexcl[4];
    const int lane = threadIdx.x & 63;
    const int wid = threadIdx.x >> 6;
    int idx = blockIdx.x * 256 + threadIdx.x;
    int4 v = make_int4(0, 0, 0, 0);
    if (idx < M4) v = reinterpret_cast<const int4*>(cnt)[idx];
    int ts = v.x + v.y + v.z + v.w;
    int incl = ts;
#pragma unroll
    for (int off = 1; off < 64; off <<= 1) {
        int t = __shfl_up(incl, off, 64);
        if (lane >= off) incl += t;
    }
    if (lane == 63) wsum[wid] = incl;
    __syncthreads();
    if (threadIdx.x < 4) {
        int e = 0;
        for (int i = 0; i < (int)threadIdx.x; ++i) e += wsum[i];
        wexcl[threadIdx.x] = e;
    }
    __syncthreads();
    if (idx < M4) {
        int base = bsum[blockIdx.x] + wexcl[wid] + (incl - ts);
        int4 o;
        o.x = base;
        o.y = base + v.x;
        o.z = base + v.x + v.y;
        o.w = base + v.x + v.y + v.z;
        reinterpret_cast<int4*>(rp)[idx] = o;
    }
}

// ---------------- CSR build: fill (rp becomes end-offsets afterwards) -------
__global__ __launch_bounds__(256) void k_fill(
    const int* __restrict__ src, const int* __restrict__ dst,
    int* __restrict__ rp, int* __restrict__ csr, int E)
{
    int e = blockIdx.x * 256 + threadIdx.x;
    if (e < E) {
        int pos = atomicAdd(rp + dst[e], 1);
        csr[pos] = src[e];
    }
}

// ---------------- gather segment-mean -> bf16 ----------------
template <bool INF32>
__global__ __launch_bounds__(256) void k_gather_agg(
    const void* __restrict__ hv, const int* __restrict__ csr,
    const int* __restrict__ rp_end, const int* __restrict__ cnt,
    unsigned short* __restrict__ agg, int M)
{
    int d = blockIdx.x * 4 + (threadIdx.x >> 6);
    if (d >= M) return;
    int lane = threadIdx.x & 63;
    int c = cnt[d], end = rp_end[d], start = end - c;
    float a0 = 0.f, a1 = 0.f, a2 = 0.f, a3 = 0.f;
    for (int chunk = start; chunk < end; chunk += 64) {
        int n = end - chunk; if (n > 64) n = 64;
        int mysrc = (lane < n) ? csr[chunk + lane] : 0;
#pragma unroll 4
        for (int e = 0; e < n; ++e) {
            int s = __shfl(mysrc, e, 64);
            if constexpr (INF32) {
                float4 v = reinterpret_cast<const float4*>(
                    (const float*)hv + (size_t)s * 256)[lane];
                a0 += v.x; a1 += v.y; a2 += v.z; a3 += v.w;
            } else {
                uint2 v = reinterpret_cast<const uint2*>(
                    (const unsigned short*)hv + (size_t)s * 256)[lane];
                a0 += bu2f_lo(v.x); a1 += bu2f_hi(v.x);
                a2 += bu2f_lo(v.y); a3 += bu2f_hi(v.y);
            }
        }
    }
    float inv = 1.0f / (float)(c > 1 ? c : 1);
    ushort4 o;
    o.x = f2bu(a0 * inv); o.y = f2bu(a1 * inv);
    o.z = f2bu(a2 * inv); o.w = f2bu(a3 * inv);
    *reinterpret_cast<ushort4*>(agg + (size_t)d * 256 + lane * 4) = o;
}

// ---------------- weight prep: WT[n][k] bf16, k<256 self / k>=256 neigh ----
__global__ __launch_bounds__(256) void k_prep_wt(
    const float* __restrict__ Ws, const float* __restrict__ Wn,
    unsigned short* __restrict__ WT, int N)
{
    int idx = blockIdx.x * 256 + threadIdx.x;
    if (idx >= N * 512) return;
    int n = idx >> 9, k = idx & 511;
    float v = (k < 256) ? Ws[k * N + n] : Wn[(k - 256) * N + n];
    WT[idx] = f2bu(v);
}

// ---------------- cast f32 -> bf16 (8 elems/thread) ----------------
__global__ __launch_bounds__(256) void k_cast_f2b(
    const float4* __restrict__ in, uint4* __restrict__ out, int nOct)
{
    int i = blockIdx.x * 256 + threadIdx.x;
    if (i >= nOct) return;
    float4 a = in[2 * i], b = in[2 * i + 1];
    uint4 o;
    o.x = (unsigned)f2bu(a.x) | ((unsigned)f2bu(a.y) << 16);
    o.y = (unsigned)f2bu(a.z) | ((unsigned)f2bu(a.w) << 16);
    o.z = (unsigned)f2bu(b.x) | ((unsigned)f2bu(b.y) << 16);
    o.w = (unsigned)f2bu(b.z) | ((unsigned)f2bu(b.w) << 16);
    out[i] = o;
}

// ---------------- MFMA dual-GEMM: out = act([A0|A1] @ WT^T + b) ----------------
// K = 512 (k<256 from A0, k>=256 from A1). BM=BN=128, BK=64.
// 4 waves, each 64x64 sub-tile = 4x4 frags of 16x16x32 bf16 MFMA.
// LDS pitch 72 bf16 (144 B) -> <=2-way bank aliasing on ds_read_b128 (free).
template <int ACT, bool A0F32, bool OUTF32>
__global__ __launch_bounds__(256) void k_mfma_gemm(
    const void* __restrict__ A0v, const unsigned short* __restrict__ A1,
    const unsigned short* __restrict__ WT, const float* __restrict__ bias,
    void* __restrict__ outv, int M, int N)
{
    __shared__ unsigned short sA[128 * 72];
    __shared__ unsigned short sB[128 * 72];
    const int tid = threadIdx.x;
    const int lane = tid & 63;
    const int w = tid >> 6;
    const int wr = w >> 1, wc = w & 1;
    const int row0 = blockIdx.x * 128;
    const int col0 = blockIdx.y * 128;

    f32x4 acc[4][4] = {};

    for (int p = 0; p < 8; ++p) {
        const int kc0 = p * 64;
        if (kc0 < 256) {
            if constexpr (A0F32) {
                const float* src = (const float*)A0v;
#pragma unroll
                for (int ps = 0; ps < 8; ++ps) {
                    int flat = (ps * 256 + tid) * 4;
                    int r = flat >> 6, cc = flat & 63;
                    int row = row0 + r; row = row < M ? row : M - 1;
                    float4 v = *reinterpret_cast<const float4*>(
                        src + (size_t)row * 256 + kc0 + cc);
                    ushort4 b4;
                    b4.x = f2bu(v.x); b4.y = f2bu(v.y);
                    b4.z = f2bu(v.z); b4.w = f2bu(v.w);
                    *reinterpret_cast<ushort4*>(&sA[r * 72 + cc]) = b4;
                }
            } else {
                const unsigned short* src = (const unsigned short*)A0v;
#pragma unroll
                for (int ps = 0; ps < 4; ++ps) {
                    int f8 = ps * 256 + tid;
                    int r = f8 >> 3, c8 = f8 & 7;
                    int row = row0 + r; row = row < M ? row : M - 1;
                    uint4 v = *reinterpret_cast<const uint4*>(
                        src + (size_t)row * 256 + kc0 + c8 * 8);
                    *reinterpret_cast<uint4*>(&sA[r * 72 + c8 * 8]) = v;
                }
            }
        } else {
#pragma unroll
            for (int ps = 0; ps < 4; ++ps) {
                int f8 = ps * 256 + tid;
                int r = f8 >> 3, c8 = f8 & 7;
                int row = row0 + r; row = row < M ? row : M - 1;
                uint4 v = *reinterpret_cast<const uint4*>(
                    A1 + (size_t)row * 256 + (kc0 - 256) + c8 * 8);
                *reinterpret_cast<uint4*>(&sA[r * 72 + c8 * 8]) = v;
            }
        }
#pragma unroll
        for (int ps = 0; ps < 4; ++ps) {
            int f8 = ps * 256 + tid;
            int r = f8 >> 3, c8 = f8 & 7;
            uint4 v = *reinterpret_cast<const uint4*>(
                WT + (size_t)(col0 + r) * 512 + kc0 + c8 * 8);
            *reinterpret_cast<uint4*>(&sB[r * 72 + c8 * 8]) = v;
        }
        __syncthreads();
#pragma unroll
        for (int ks = 0; ks < 64; ks += 32) {
            const int lr = lane & 15;
            const int kk = ks + (lane >> 4) * 8;
            bf8v af[4], bfr[4];
#pragma unroll
            for (int m = 0; m < 4; ++m)
                af[m] = *reinterpret_cast<const bf8v*>(
                    &sA[(wr * 64 + m * 16 + lr) * 72 + kk]);
#pragma unroll
            for (int n = 0; n < 4; ++n)
                bfr[n] = *reinterpret_cast<const bf8v*>(
                    &sB[(wc * 64 + n * 16 + lr) * 72 + kk]);
#pragma unroll
            for (int m = 0; m < 4; ++m)
#pragma unroll
                for (int n = 0; n < 4; ++n)
                    acc[m][n] = __builtin_amdgcn_mfma_f32_16x16x32_bf16(
                        af[m], bfr[n], acc[m][n], 0, 0, 0);
        }
        __syncthreads();
    }

    const int lc = lane & 15;
    const int lr4 = (lane >> 4) * 4;
#pragma unroll
    for (int n = 0; n < 4; ++n) {
        int col = col0 + wc * 64 + n * 16 + lc;
        float bb = bias[col];
#pragma unroll
        for (int m = 0; m < 4; ++m) {
#pragma unroll
            for (int j = 0; j < 4; ++j) {
                int row = row0 + wr * 64 + m * 16 + lr4 + j;
                if (row < M) {
                    float v = acc[m][n][j] + bb;
                    if (ACT) v = fmaxf(v, 0.f);
                    if constexpr (OUTF32)
                        ((float*)outv)[(size_t)row * N + col] = v;
                    else
                        ((unsigned short*)outv)[(size_t)row * N + col] = f2bu(v);
                }
            }
        }
    }
}

static inline void run_scan(const int* cnt, int* bsum, int* rp, int M,
                            hipStream_t stream) {
    int M4 = M / 4;                       // all M are divisible by 4
    int B = (M4 + 255) / 256;             // blocks of 1024 ints
    k_bsum<<<B, 256, 0, stream>>>(cnt, bsum, M4);
    k_bscan<<<1, 256, 0, stream>>>(bsum, B);
    k_bapply<<<B, 256, 0, stream>>>(cnt, bsum, rp, M4);
}

extern "C" void kernel_launch(void* const* d_in, const int* in_sizes, int n_in,
                              void* d_out, int out_size, void* d_ws, size_t ws_size,
                              hipStream_t stream) {
    const float* feat = (const float*)d_in[0];
    const int* e0s = (const int*)d_in[1];
    const int* e0d = (const int*)d_in[2];
    const int* e1s = (const int*)d_in[3];
    const int* e1d = (const int*)d_in[4];
    const int* e2s = (const int*)d_in[5];
    const int* e2d = (const int*)d_in[6];
    const float* ws0 = (const float*)d_in[7];
    const float* wn0 = (const float*)d_in[8];
    const float* b0 = (const float*)d_in[9];
    const float* ws1 = (const float*)d_in[10];
    const float* wn1 = (const float*)d_in[11];
    const float* b1 = (const float*)d_in[12];
    const float* ws2 = (const float*)d_in[13];
    const float* wn2 = (const float*)d_in[14];
    const float* b2 = (const float*)d_in[15];
    float* out = (float*)d_out;

    char* base = (char*)d_ws;
    const bool big = ws_size >= 325000000ull;
    unsigned short* featbf = nullptr;
    size_t off = 0;
    if (big) { featbf = (unsigned short*)base; off += 204800000ull; }
    unsigned short* aggb = (unsigned short*)(base + off); off += 51200000ull;
    unsigned short* h1b  = (unsigned short*)(base + off); off += 51200000ull;
    unsigned short* h2b  = (unsigned short*)(base + off); off += 10240000ull;
    unsigned short* wt0  = (unsigned short*)(base + off); off += 262144ull;
    unsigned short* wt1  = (unsigned short*)(base + off); off += 262144ull;
    unsigned short* wt2  = (unsigned short*)(base + off); off += 131072ull;
    int* csr = (int*)(base + off); off += 6000000ull;
    int* cnt = (int*)(base + off); off += 400000ull;
    int* rp  = (int*)(base + off); off += 400000ull;
    int* bsum = (int*)(base + off); off += 1024ull;

    k_prep_wt<<<512, 256, 0, stream>>>(ws0, wn0, wt0, 256);
    k_prep_wt<<<512, 256, 0, stream>>>(ws1, wn1, wt1, 256);
    k_prep_wt<<<256, 256, 0, stream>>>(ws2, wn2, wt2, 128);
    if (big)
        k_cast_f2b<<<50000, 256, 0, stream>>>(
            (const float4*)feat, (uint4*)featbf, 12800000);

    // ---- layer 0: feat[400K] --(E0)--> h1b[100K], ReLU ----
    hipMemsetAsync(cnt, 0, (size_t)kN1 * 4, stream);
    k_count<<<(kE0 + 255) / 256, 256, 0, stream>>>(e0d, cnt, kE0);
    run_scan(cnt, bsum, rp, kN1, stream);
    k_fill<<<(kE0 + 255) / 256, 256, 0, stream>>>(e0s, e0d, rp, csr, kE0);
    if (big) {
        k_gather_agg<false><<<(kN1 + 3) / 4, 256, 0, stream>>>(
            featbf, csr, rp, cnt, aggb, kN1);
        k_mfma_gemm<1, false, false><<<dim3(782, 2), 256, 0, stream>>>(
            featbf, aggb, wt0, b0, h1b, kN1, 256);
    } else {
        k_gather_agg<true><<<(kN1 + 3) / 4, 256, 0, stream>>>(
            feat, csr, rp, cnt, aggb, kN1);
        k_mfma_gemm<1, true, false><<<dim3(782, 2), 256, 0, stream>>>(
            feat, aggb, wt0, b0, h1b, kN1, 256);
    }

    // ---- layer 1: h1b[100K] --(E1)--> h2b[20K], ReLU ----
    hipMemsetAsync(cnt, 0, (size_t)kN2 * 4, stream);
    k_count<<<(kE1 + 255) / 256, 256, 0, stream>>>(e1d, cnt, kE1);
    run_scan(cnt, bsum, rp, kN2, stream);
    k_fill<<<(kE1 + 255) / 256, 256, 0, stream>>>(e1s, e1d, rp, csr, kE1);
    k_gather_agg<false><<<(kN2 + 3) / 4, 256, 0, stream>>>(
        h1b, csr, rp, cnt, aggb, kN2);
    k_mfma_gemm<1, false, false><<<dim3(157, 2), 256, 0, stream>>>(
        h1b, aggb, wt1, b1, h2b, kN2, 256);

    // ---- layer 2: h2b[20K] --(E2)--> out[4096], no act, f32 out ----
    hipMemsetAsync(cnt, 0, (size_t)kN3 * 4, stream);
    k_count<<<(kE2 + 255) / 256, 256, 0, stream>>>(e2d, cnt, kE2);
    run_scan(cnt, bsum, rp, kN3, stream);
    k_fill<<<(kE2 + 255) / 256, 256, 0, stream>>>(e2s, e2d, rp, csr, kE2);
    k_gather_agg<false><<<(kN3 + 3) / 4, 256, 0, stream>>>(
        h2b, csr, rp, cnt, aggb, kN3);
    k_mfma_gemm<0, false, true><<<dim3(32, 1), 256, 0, stream>>>(
        h2b, aggb, wt2, b2, out, kN3, 128);
}

// Round 5
// 564.781 us; speedup vs baseline: 12.6459x; 1.1315x over previous
//
#include <hip/hip_runtime.h>
#include <hip/hip_bf16.h>

// GraphSAGE 3-layer, eval mode.
// Round 5: merged front-end (cast || 3x count || weight prep in ONE dispatch),
// merged 3-layer scan/fill, 2-edge-per-iter uint4 gather. 12 dispatches total.

static constexpr int kN1 = 100000, kN2 = 20000, kN3 = 4096;
static constexpr int kE0 = 1500000, kE1 = 200000, kE2 = 40960;

using bf8v  = __attribute__((ext_vector_type(8))) short;   // 8 bf16 (4 VGPR)
using f32x4 = __attribute__((ext_vector_type(4))) float;   // MFMA acc

__device__ __forceinline__ unsigned short f2bu(float f) {
    __hip_bfloat16 h = __float2bfloat16(f);
    return *reinterpret_cast<unsigned short*>(&h);
}
__device__ __forceinline__ float bu2f_lo(unsigned u) {
    unsigned b = u << 16; return *reinterpret_cast<float*>(&b);
}
__device__ __forceinline__ float bu2f_hi(unsigned u) {
    unsigned b = u & 0xffff0000u; return *reinterpret_cast<float*>(&b);
}

// section block counts
static constexpr int CB  = 50000;                 // cast: 12.8M uint4 / 256
static constexpr int C0B = (kE0 + 255) / 256;     // 5860
static constexpr int C1B = (kE1 + 255) / 256;     // 782
static constexpr int C2B = (kE2 + 255) / 256;     // 160
static constexpr int PW0B = 512, PW1B = 512, PW2B = 256;
// scan geometry (ints4 per layer)
static constexpr int M4_0 = kN1 / 4, M4_1 = kN2 / 4, M4_2 = kN3 / 4;
static constexpr int B0 = (M4_0 + 255) / 256;     // 98
static constexpr int B1 = (M4_1 + 255) / 256;     // 20
static constexpr int B2 = (M4_2 + 255) / 256;     // 4

// ---------------- phase 0: cast feat->bf16 || count x3 || weight-prep x3 ----
template <bool BIG>
__global__ __launch_bounds__(256) void k_phase0(
    const float4* __restrict__ feat4, uint4* __restrict__ featbf,
    const int* __restrict__ e0d, const int* __restrict__ e1d,
    const int* __restrict__ e2d,
    int* __restrict__ cnt0, int* __restrict__ cnt1, int* __restrict__ cnt2,
    const float* __restrict__ ws0, const float* __restrict__ wn0,
    const float* __restrict__ ws1, const float* __restrict__ wn1,
    const float* __restrict__ ws2, const float* __restrict__ wn2,
    unsigned short* __restrict__ wt0, unsigned short* __restrict__ wt1,
    unsigned short* __restrict__ wt2)
{
    int b = blockIdx.x;
    const int tid = threadIdx.x;
    if (BIG) {
        if (b < CB) {  // cast: 8 f32 -> 8 bf16 per thread
            int i = b * 256 + tid;
            float4 a = feat4[2 * i], c = feat4[2 * i + 1];
            uint4 o;
            o.x = (unsigned)f2bu(a.x) | ((unsigned)f2bu(a.y) << 16);
            o.y = (unsigned)f2bu(a.z) | ((unsigned)f2bu(a.w) << 16);
            o.z = (unsigned)f2bu(c.x) | ((unsigned)f2bu(c.y) << 16);
            o.w = (unsigned)f2bu(c.z) | ((unsigned)f2bu(c.w) << 16);
            featbf[i] = o;
            return;
        }
        b -= CB;
    }
    if (b < C0B) {
        int e = b * 256 + tid;
        if (e < kE0) atomicAdd(cnt0 + e0d[e], 1);
        return;
    }
    b -= C0B;
    if (b < C1B) {
        int e = b * 256 + tid;
        if (e < kE1) atomicAdd(cnt1 + e1d[e], 1);
        return;
    }
    b -= C1B;
    if (b < C2B) {
        int e = b * 256 + tid;
        if (e < kE2) atomicAdd(cnt2 + e2d[e], 1);
        return;
    }
    b -= C2B;
    if (b < PW0B) {
        int idx = b * 256 + tid;            // < 131072
        int n = idx >> 9, k = idx & 511;
        wt0[idx] = f2bu(k < 256 ? ws0[k * 256 + n] : wn0[(k - 256) * 256 + n]);
        return;
    }
    b -= PW0B;
    if (b < PW1B) {
        int idx = b * 256 + tid;
        int n = idx >> 9, k = idx & 511;
        wt1[idx] = f2bu(k < 256 ? ws1[k * 256 + n] : wn1[(k - 256) * 256 + n]);
        return;
    }
    b -= PW1B;
    {
        int idx = b * 256 + tid;            // < 65536
        int n = idx >> 9, k = idx & 511;
        wt2[idx] = f2bu(k < 256 ? ws2[k * 128 + n] : wn2[(k - 256) * 128 + n]);
    }
}

// ---------------- merged scan phase 1: per-1024-int block sums --------------
__global__ __launch_bounds__(256) void k_bsum_all(
    const int* __restrict__ cnt0, const int* __restrict__ cnt1,
    const int* __restrict__ cnt2, int* __restrict__ bsum)
{
    const int* cnt; int lb, M4, bo;
    int b = blockIdx.x;
    if (b < B0)            { cnt = cnt0; lb = b;            M4 = M4_0; bo = 0; }
    else if (b < B0 + B1)  { cnt = cnt1; lb = b - B0;       M4 = M4_1; bo = B0; }
    else                   { cnt = cnt2; lb = b - B0 - B1;  M4 = M4_2; bo = B0 + B1; }
    __shared__ int wsum[4];
    int idx = lb * 256 + threadIdx.x;
    int ts = 0;
    if (idx < M4) {
        int4 v = reinterpret_cast<const int4*>(cnt)[idx];
        ts = v.x + v.y + v.z + v.w;
    }
#pragma unroll
    for (int off = 32; off > 0; off >>= 1) ts += __shfl_down(ts, off, 64);
    if ((threadIdx.x & 63) == 0) wsum[threadIdx.x >> 6] = ts;
    __syncthreads();
    if (threadIdx.x == 0)
        bsum[bo + lb] = wsum[0] + wsum[1] + wsum[2] + wsum[3];
}

// ---------------- merged scan phase 2: exclusive-scan 3 regions -------------
__global__ __launch_bounds__(256) void k_bscan_all(int* __restrict__ bsum)
{
    __shared__ int s[B0 + B1 + B2];
    const int total = B0 + B1 + B2;
    if (threadIdx.x < total) s[threadIdx.x] = bsum[threadIdx.x];
    __syncthreads();
    if (threadIdx.x < 3) {
        int lo = threadIdx.x == 0 ? 0 : (threadIdx.x == 1 ? B0 : B0 + B1);
        int hi = threadIdx.x == 0 ? B0 : (threadIdx.x == 1 ? B0 + B1 : total);
        int run = 0;
        for (int i = lo; i < hi; ++i) { int v = s[i]; s[i] = run; run += v; }
    }
    __syncthreads();
    if (threadIdx.x < total) bsum[threadIdx.x] = s[threadIdx.x];
}

// ---------------- merged scan phase 3: apply -> exclusive offsets rp --------
__global__ __launch_bounds__(256) void k_bapply_all(
    const int* __restrict__ cnt0, const int* __restrict__ cnt1,
    const int* __restrict__ cnt2, const int* __restrict__ bsum,
    int* __restrict__ rp0, int* __restrict__ rp1, int* __restrict__ rp2)
{
    const int* cnt; int* rp; int lb, M4, bo;
    int b = blockIdx.x;
    if (b < B0)            { cnt = cnt0; rp = rp0; lb = b;           M4 = M4_0; bo = 0; }
    else if (b < B0 + B1)  { cnt = cnt1; rp = rp1; lb = b - B0;      M4 = M4_1; bo = B0; }
    else                   { cnt = cnt2; rp = rp2; lb = b - B0 - B1; M4 = M4_2; bo = B0 + B1; }
    __shared__ int wsum[4];
    __shared__ int wexcl[4];
    const int lane = threadIdx.x & 63;
    const int wid = threadIdx.x >> 6;
    int idx = lb * 256 + threadIdx.x;
    int4 v = make_int4(0, 0, 0, 0);
    if (idx < M4) v = reinterpret_cast<const int4*>(cnt)[idx];
    int ts = v.x + v.y + v.z + v.w;
    int incl = ts;
#pragma unroll
    for (int off = 1; off < 64; off <<= 1) {
        int t = __shfl_up(incl, off, 64);
        if (lane >= off) incl += t;
    }
    if (lane == 63) wsum[wid] = incl;
    __syncthreads();
    if (threadIdx.x < 4) {
        int e = 0;
        for (int i = 0; i < (int)threadIdx.x; ++i) e += wsum[i];
        wexcl[threadIdx.x] = e;
    }
    __syncthreads();
    if (idx < M4) {
        int base = bsum[bo + lb] + wexcl[wid] + (incl - ts);
        int4 o;
        o.x = base;
        o.y = base + v.x;
        o.z = base + v.x + v.y;
        o.w = base + v.x + v.y + v.z;
        reinterpret_cast<int4*>(rp)[idx] = o;
    }
}

// ---------------- merged fill: rp becomes end-offsets afterwards ------------
__global__ __launch_bounds__(256) void k_fill_all(
    const int* __restrict__ e0s, const int* __restrict__ e0d,
    const int* __restrict__ e1s, const int* __restrict__ e1d,
    const int* __restrict__ e2s, const int* __restrict__ e2d,
    int* __restrict__ rp0, int* __restrict__ rp1, int* __restrict__ rp2,
    int* __restrict__ csr0, int* __restrict__ csr1, int* __restrict__ csr2)
{
    int b = blockIdx.x;
    const int* src; const int* dst; int* rp; int* csr; int E, lb;
    if (b < C0B)            { src = e0s; dst = e0d; rp = rp0; csr = csr0; E = kE0; lb = b; }
    else if (b < C0B + C1B) { src = e1s; dst = e1d; rp = rp1; csr = csr1; E = kE1; lb = b - C0B; }
    else                    { src = e2s; dst = e2d; rp = rp2; csr = csr2; E = kE2; lb = b - C0B - C1B; }
    int e = lb * 256 + threadIdx.x;
    if (e < E) {
        int pos = atomicAdd(rp + dst[e], 1);
        csr[pos] = src[e];
    }
}

// ---------------- gather segment-mean -> bf16 (bf16 src, 2 edges/iter) ------
// wave = 1 dst row. half-wave h processes edge e+h; lane&31 owns 8 feats.
__global__ __launch_bounds__(256) void k_gather_agg_b(
    const unsigned short* __restrict__ h, const int* __restrict__ csr,
    const int* __restrict__ rp_end, const int* __restrict__ cnt,
    unsigned short* __restrict__ agg, int M)
{
    int d = blockIdx.x * 4 + (threadIdx.x >> 6);
    if (d >= M) return;
    const int lane = threadIdx.x & 63;
    const int half = lane >> 5;
    const int l32 = lane & 31;
    int c = cnt[d], end = rp_end[d], start = end - c;
    float a[8] = {0.f, 0.f, 0.f, 0.f, 0.f, 0.f, 0.f, 0.f};
    for (int chunk = start; chunk < end; chunk += 64) {
        int n = end - chunk; if (n > 64) n = 64;
        int mysrc = (lane < n) ? csr[chunk + lane] : 0;
#pragma unroll 2
        for (int e = 0; e < n; e += 2) {
            int ie = e + half;
            int s = __shfl(mysrc, ie, 64);
            if (ie < n) {
                uint4 v = *reinterpret_cast<const uint4*>(
                    h + (size_t)s * 256 + l32 * 8);
                a[0] += bu2f_lo(v.x); a[1] += bu2f_hi(v.x);
                a[2] += bu2f_lo(v.y); a[3] += bu2f_hi(v.y);
                a[4] += bu2f_lo(v.z); a[5] += bu2f_hi(v.z);
                a[6] += bu2f_lo(v.w); a[7] += bu2f_hi(v.w);
            }
        }
    }
#pragma unroll
    for (int j = 0; j < 8; ++j) a[j] += __shfl(a[j], lane ^ 32, 64);
    if (half == 0) {
        float inv = 1.0f / (float)(c > 1 ? c : 1);
        uint4 o;
        o.x = (unsigned)f2bu(a[0] * inv) | ((unsigned)f2bu(a[1] * inv) << 16);
        o.y = (unsigned)f2bu(a[2] * inv) | ((unsigned)f2bu(a[3] * inv) << 16);
        o.z = (unsigned)f2bu(a[4] * inv) | ((unsigned)f2bu(a[5] * inv) << 16);
        o.w = (unsigned)f2bu(a[6] * inv) | ((unsigned)f2bu(a[7] * inv) << 16);
        *reinterpret_cast<uint4*>(agg + (size_t)d * 256 + l32 * 8) = o;
    }
}

// f32-src fallback (small-ws path), one edge/iter
__global__ __launch_bounds__(256) void k_gather_agg_f(
    const float* __restrict__ h, const int* __restrict__ csr,
    const int* __restrict__ rp_end, const int* __restrict__ cnt,
    unsigned short* __restrict__ agg, int M)
{
    int d = blockIdx.x * 4 + (threadIdx.x >> 6);
    if (d >= M) return;
    int lane = threadIdx.x & 63;
    int c = cnt[d], end = rp_end[d], start = end - c;
    float a0 = 0.f, a1 = 0.f, a2 = 0.f, a3 = 0.f;
    for (int chunk = start; chunk < end; chunk += 64) {
        int n = end - chunk; if (n > 64) n = 64;
        int mysrc = (lane < n) ? csr[chunk + lane] : 0;
#pragma unroll 4
        for (int e = 0; e < n; ++e) {
            int s = __shfl(mysrc, e, 64);
            float4 v = reinterpret_cast<const float4*>(h + (size_t)s * 256)[lane];
            a0 += v.x; a1 += v.y; a2 += v.z; a3 += v.w;
        }
    }
    float inv = 1.0f / (float)(c > 1 ? c : 1);
    ushort4 o;
    o.x = f2bu(a0 * inv); o.y = f2bu(a1 * inv);
    o.z = f2bu(a2 * inv); o.w = f2bu(a3 * inv);
    *reinterpret_cast<ushort4*>(agg + (size_t)d * 256 + lane * 4) = o;
}

// ---------------- MFMA dual-GEMM: out = act([A0|A1] @ WT^T + b) ----------------
// K = 512 (k<256 from A0, k>=256 from A1). BM=BN=128, BK=64.
// 4 waves, each 64x64 sub-tile = 4x4 frags of 16x16x32 bf16 MFMA.
// LDS pitch 72 bf16 (144 B) -> <=2-way bank aliasing on ds_read_b128 (free).
template <int ACT, bool A0F32, bool OUTF32>
__global__ __launch_bounds__(256) void k_mfma_gemm(
    const void* __restrict__ A0v, const unsigned short* __restrict__ A1,
    const unsigned short* __restrict__ WT, const float* __restrict__ bias,
    void* __restrict__ outv, int M, int N)
{
    __shared__ unsigned short sA[128 * 72];
    __shared__ unsigned short sB[128 * 72];
    const int tid = threadIdx.x;
    const int lane = tid & 63;
    const int w = tid >> 6;
    const int wr = w >> 1, wc = w & 1;
    const int row0 = blockIdx.x * 128;
    const int col0 = blockIdx.y * 128;

    f32x4 acc[4][4] = {};

    for (int p = 0; p < 8; ++p) {
        const int kc0 = p * 64;
        if (kc0 < 256) {
            if constexpr (A0F32) {
                const float* src = (const float*)A0v;
#pragma unroll
                for (int ps = 0; ps < 8; ++ps) {
                    int flat = (ps * 256 + tid) * 4;
                    int r = flat >> 6, cc = flat & 63;
                    int row = row0 + r; row = row < M ? row : M - 1;
                    float4 v = *reinterpret_cast<const float4*>(
                        src + (size_t)row * 256 + kc0 + cc);
                    ushort4 b4;
                    b4.x = f2bu(v.x); b4.y = f2bu(v.y);
                    b4.z = f2bu(v.z); b4.w = f2bu(v.w);
                    *reinterpret_cast<ushort4*>(&sA[r * 72 + cc]) = b4;
                }
            } else {
                const unsigned short* src = (const unsigned short*)A0v;
#pragma unroll
                for (int ps = 0; ps < 4; ++ps) {
                    int f8 = ps * 256 + tid;
                    int r = f8 >> 3, c8 = f8 & 7;
                    int row = row0 + r; row = row < M ? row : M - 1;
                    uint4 v = *reinterpret_cast<const uint4*>(
                        src + (size_t)row * 256 + kc0 + c8 * 8);
                    *reinterpret_cast<uint4*>(&sA[r * 72 + c8 * 8]) = v;
                }
            }
        } else {
#pragma unroll
            for (int ps = 0; ps < 4; ++ps) {
                int f8 = ps * 256 + tid;
                int r = f8 >> 3, c8 = f8 & 7;
                int row = row0 + r; row = row < M ? row : M - 1;
                uint4 v = *reinterpret_cast<const uint4*>(
                    A1 + (size_t)row * 256 + (kc0 - 256) + c8 * 8);
                *reinterpret_cast<uint4*>(&sA[r * 72 + c8 * 8]) = v;
            }
        }
#pragma unroll
        for (int ps = 0; ps < 4; ++ps) {
            int f8 = ps * 256 + tid;
            int r = f8 >> 3, c8 = f8 & 7;
            uint4 v = *reinterpret_cast<const uint4*>(
                WT + (size_t)(col0 + r) * 512 + kc0 + c8 * 8);
            *reinterpret_cast<uint4*>(&sB[r * 72 + c8 * 8]) = v;
        }
        __syncthreads();
#pragma unroll
        for (int ks = 0; ks < 64; ks += 32) {
            const int lr = lane & 15;
            const int kk = ks + (lane >> 4) * 8;
            bf8v af[4], bfr[4];
#pragma unroll
            for (int m = 0; m < 4; ++m)
                af[m] = *reinterpret_cast<const bf8v*>(
                    &sA[(wr * 64 + m * 16 + lr) * 72 + kk]);
#pragma unroll
            for (int n = 0; n < 4; ++n)
                bfr[n] = *reinterpret_cast<const bf8v*>(
                    &sB[(wc * 64 + n * 16 + lr) * 72 + kk]);
#pragma unroll
            for (int m = 0; m < 4; ++m)
#pragma unroll
                for (int n = 0; n < 4; ++n)
                    acc[m][n] = __builtin_amdgcn_mfma_f32_16x16x32_bf16(
                        af[m], bfr[n], acc[m][n], 0, 0, 0);
        }
        __syncthreads();
    }

    const int lc = lane & 15;
    const int lr4 = (lane >> 4) * 4;
#pragma unroll
    for (int n = 0; n < 4; ++n) {
        int col = col0 + wc * 64 + n * 16 + lc;
        float bb = bias[col];
#pragma unroll
        for (int m = 0; m < 4; ++m) {
#pragma unroll
            for (int j = 0; j < 4; ++j) {
                int row = row0 + wr * 64 + m * 16 + lr4 + j;
                if (row < M) {
                    float v = acc[m][n][j] + bb;
                    if (ACT) v = fmaxf(v, 0.f);
                    if constexpr (OUTF32)
                        ((float*)outv)[(size_t)row * N + col] = v;
                    else
                        ((unsigned short*)outv)[(size_t)row * N + col] = f2bu(v);
                }
            }
        }
    }
}

extern "C" void kernel_launch(void* const* d_in, const int* in_sizes, int n_in,
                              void* d_out, int out_size, void* d_ws, size_t ws_size,
                              hipStream_t stream) {
    const float* feat = (const float*)d_in[0];
    const int* e0s = (const int*)d_in[1];
    const int* e0d = (const int*)d_in[2];
    const int* e1s = (const int*)d_in[3];
    const int* e1d = (const int*)d_in[4];
    const int* e2s = (const int*)d_in[5];
    const int* e2d = (const int*)d_in[6];
    const float* ws0 = (const float*)d_in[7];
    const float* wn0 = (const float*)d_in[8];
    const float* b0 = (const float*)d_in[9];
    const float* ws1 = (const float*)d_in[10];
    const float* wn1 = (const float*)d_in[11];
    const float* b1 = (const float*)d_in[12];
    const float* ws2 = (const float*)d_in[13];
    const float* wn2 = (const float*)d_in[14];
    const float* b2 = (const float*)d_in[15];
    float* out = (float*)d_out;

    char* base = (char*)d_ws;
    const bool big = ws_size >= 330000000ull;
    unsigned short* featbf = nullptr;
    size_t off = 0;
    if (big) { featbf = (unsigned short*)base; off += 204800000ull; }
    unsigned short* aggb = (unsigned short*)(base + off); off += 51200000ull;
    unsigned short* h1b  = (unsigned short*)(base + off); off += 51200000ull;
    unsigned short* h2b  = (unsigned short*)(base + off); off += 10240000ull;
    unsigned short* wt0  = (unsigned short*)(base + off); off += 262144ull;
    unsigned short* wt1  = (unsigned short*)(base + off); off += 262144ull;
    unsigned short* wt2  = (unsigned short*)(base + off); off += 131072ull;
    int* csr0 = (int*)(base + off); off += 6000000ull;
    int* csr1 = (int*)(base + off); off += 800000ull;
    int* csr2 = (int*)(base + off); off += 163840ull;
    int* cnt0 = (int*)(base + off); off += 400000ull;   // cnt0|cnt1|cnt2 contiguous
    int* cnt1 = (int*)(base + off); off += 80000ull;
    int* cnt2 = (int*)(base + off); off += 16384ull;
    int* rp0  = (int*)(base + off); off += 400000ull;
    int* rp1  = (int*)(base + off); off += 80000ull;
    int* rp2  = (int*)(base + off); off += 16384ull;
    int* bsum = (int*)(base + off); off += 512ull;      // 122 ints

    // one memset over contiguous cnt region (124096 ints)
    hipMemsetAsync(cnt0, 0, (size_t)(kN1 + kN2 + kN3) * 4, stream);

    // phase 0: cast || count x3 || prep x3
    if (big)
        k_phase0<true><<<CB + C0B + C1B + C2B + PW0B + PW1B + PW2B, 256, 0, stream>>>(
            (const float4*)feat, (uint4*)featbf, e0d, e1d, e2d,
            cnt0, cnt1, cnt2, ws0, wn0, ws1, wn1, ws2, wn2, wt0, wt1, wt2);
    else
        k_phase0<false><<<C0B + C1B + C2B + PW0B + PW1B + PW2B, 256, 0, stream>>>(
            nullptr, nullptr, e0d, e1d, e2d,
            cnt0, cnt1, cnt2, ws0, wn0, ws1, wn1, ws2, wn2, wt0, wt1, wt2);

    // merged 3-layer scan + fill
    k_bsum_all<<<B0 + B1 + B2, 256, 0, stream>>>(cnt0, cnt1, cnt2, bsum);
    k_bscan_all<<<1, 256, 0, stream>>>(bsum);
    k_bapply_all<<<B0 + B1 + B2, 256, 0, stream>>>(
        cnt0, cnt1, cnt2, bsum, rp0, rp1, rp2);
    k_fill_all<<<C0B + C1B + C2B, 256, 0, stream>>>(
        e0s, e0d, e1s, e1d, e2s, e2d, rp0, rp1, rp2, csr0, csr1, csr2);

    // ---- layer 0 ----
    if (big) {
        k_gather_agg_b<<<(kN1 + 3) / 4, 256, 0, stream>>>(
            featbf, csr0, rp0, cnt0, aggb, kN1);
        k_mfma_gemm<1, false, false><<<dim3(782, 2), 256, 0, stream>>>(
            featbf, aggb, wt0, b0, h1b, kN1, 256);
    } else {
        k_gather_agg_f<<<(kN1 + 3) / 4, 256, 0, stream>>>(
            feat, csr0, rp0, cnt0, aggb, kN1);
        k_mfma_gemm<1, true, false><<<dim3(782, 2), 256, 0, stream>>>(
            feat, aggb, wt0, b0, h1b, kN1, 256);
    }

    // ---- layer 1 ----
    k_gather_agg_b<<<(kN2 + 3) / 4, 256, 0, stream>>>(
        h1b, csr1, rp1, cnt1, aggb, kN2);
    k_mfma_gemm<1, false, false><<<dim3(157, 2), 256, 0, stream>>>(
        h1b, aggb, wt1, b1, h2b, kN2, 256);

    // ---- layer 2 ----
    k_gather_agg_b<<<(kN3 + 3) / 4, 256, 0, stream>>>(
        h2b, csr2, rp2, cnt2, aggb, kN3);
    k_mfma_gemm<0, false, true><<<dim3(32, 1), 256, 0, stream>>>(
        h2b, aggb, wt2, b2, out, kN3, 128);
}